// Round 13
// baseline (292.739 us; speedup 1.0000x reference)
//
#include <hip/hip_runtime.h>
#include <math.h>

#define B_  2
#define L_  2048
#define D_  1024
#define H_  16
#define DH_ 64
#define BL_ (B_*L_)   // 4096

typedef unsigned short u16;
typedef __attribute__((ext_vector_type(8))) short short8;
typedef __attribute__((ext_vector_type(4))) float f32x4;
typedef __attribute__((ext_vector_type(4))) unsigned short u16x4;

template<bool V> struct BC { static constexpr bool value = V; };

// ---- workspace offsets (floats)
#define WS_XB   0            // x bf16 [4096][1024]
#define WS_WT4  2097152      // Wt bf16 [4][1024][1024]
#define WS_QB   4194304      // [32][2048][64] bf16
#define WS_KB   6291456
#define WS_VT   8388608      // [32][64][2048] bf16
#define WS_AOB  10485760     // AO bf16 [4096][1024]
#define WS_COS  12582912     // [2048][32] f32
#define WS_SIN  12648448
#define WS_PBL  12713984     // [2048] f32 (pre-scaled by log2e)
// end ~12.72M floats ~ 50.9 MB

__device__ __forceinline__ u16 f2b(float f) {
  union { float f; unsigned u; } v; v.f = f;
  unsigned r = (v.u + 0x7fffu + ((v.u >> 16) & 1u)) >> 16;
  return (u16)r;
}
__device__ __forceinline__ u16x4 f2b4(float a, float b, float c, float d) {
  u16x4 u; u.x = f2b(a); u.y = f2b(b); u.z = f2b(c); u.w = f2b(d); return u;
}
__device__ __forceinline__ float bf2f(u16 u) {
  union { unsigned u; float f; } v; v.u = ((unsigned)u) << 16; return v.f;
}
__device__ __forceinline__ void gl_lds16(const void* g, void* l) {
  __builtin_amdgcn_global_load_lds(
      (const __attribute__((address_space(1))) unsigned int*)g,
      (__attribute__((address_space(3))) unsigned int*)l, 16, 0, 0);
}
__device__ __forceinline__ void nt_store4(float x, float y, float z, float w, float* p) {
  f32x4 v = (f32x4){x, y, z, w};
  __builtin_nontemporal_store(v, (f32x4*)p);
}

// ---------------------------------------------------------------- tables
__global__ void fill_tables(float* __restrict__ costab, float* __restrict__ sintab,
                            float* __restrict__ pbl) {
  int idx = blockIdx.x * 256 + threadIdx.x;
  if (idx < L_ * 32) {
    int l = idx >> 5, tp = idx & 31;
    double inv = pow(10000.0, -2.0 * (double)tp / 64.0);
    double th  = (double)l * inv;
    costab[idx] = (float)cos(th);
    sintab[idx] = (float)sin(th);
  }
  if (idx < L_) {
    double d = (double)idx;
    double v = 0.5  * cos(6.283185307179586 * d / 24.0)
             + 0.25 * cos(6.283185307179586 * d / 168.0);
    pbl[idx] = (float)(v * 1.4426950408889634);
  }
}

// ---------------------------------------------------------------- x -> bf16
__global__ __launch_bounds__(256) void xcast(const float* __restrict__ x, u16* __restrict__ xb) {
  const size_t i = ((size_t)blockIdx.x * 256 + threadIdx.x) * 8;
  float4 a = *(const float4*)(x + i);
  float4 b = *(const float4*)(x + i + 4);
  u16 us[8] = { f2b(a.x),f2b(a.y),f2b(a.z),f2b(a.w), f2b(b.x),f2b(b.y),f2b(b.z),f2b(b.w) };
  *(short8*)(xb + i) = *(short8*)us;
}

// ---------------------------------------------------------------- W[k][n] f32 -> Wt[n][k] bf16 (4 weights, z-indexed)
__global__ __launch_bounds__(256) void wtrans4(const float* __restrict__ W0, const float* __restrict__ W1,
                                               const float* __restrict__ W2, const float* __restrict__ W3,
                                               u16* __restrict__ Wt) {
  __shared__ u16 tt[64][80];
  const int z = blockIdx.z;
  const float* W = (z == 0) ? W0 : (z == 1) ? W1 : (z == 2) ? W2 : W3;
  u16* Wtz = Wt + (size_t)z * 1024 * 1024;
  const int k0 = blockIdx.x << 6, n0 = blockIdx.y << 6;
  const int t = threadIdx.x;
  {
    const int r = t >> 4, c4 = (t & 15) << 2;
    for (int rr = r; rr < 64; rr += 16) {
      float4 v = *(const float4*)(W + (size_t)(k0 + rr) * D_ + n0 + c4);
      tt[c4+0][rr] = f2b(v.x); tt[c4+1][rr] = f2b(v.y);
      tt[c4+2][rr] = f2b(v.z); tt[c4+3][rr] = f2b(v.w);
    }
  }
  __syncthreads();
  const int n = t >> 2, kc = (t & 3) << 4;
  u16* dst = Wtz + (size_t)(n0 + n) * D_ + k0 + kc;
  #pragma unroll
  for (int u = 0; u < 16; ++u) dst[u] = tt[n][kc + u];
}

// ---------------------------------------------------------------- bf16 MFMA GEMM, 128x128 tile, BK=64
// XCD-bijective swizzle: each XCD owns a contiguous gy-range (W panels resident in its L2).
template<int KIND>
__global__ __launch_bounds__(256) void gemm_k(
    const u16* __restrict__ Ag, const u16* __restrict__ Bg,
    const float* __restrict__ b0, const float* __restrict__ b1, const float* __restrict__ b2,
    const float* __restrict__ costab, const float* __restrict__ sintab,
    u16* __restrict__ O0, u16* __restrict__ O1, u16* __restrict__ O2,
    float* __restrict__ Cout)
{
  __shared__ u16 As[8192];
  __shared__ u16 Bs[8192];
  const int t = threadIdx.x, w = t >> 6, lane = t & 63;
  const int lt = lane & 15, lg = lane >> 4;
  const int wg = blockIdx.x + (blockIdx.y << 5);
  int sid;
  if constexpr (KIND == 1) sid = (wg & 7) * 96 + (wg >> 3);   // 768 blocks, 3 gy per XCD
  else                     sid = (wg & 7) * 32 + (wg >> 3);   // 256 blocks, 1 gy per XCD
  const int row0 = (sid & 31) << 7;
  const int gy   = sid >> 5;
  const int col0 = gy << 7;
  const int wm = (w & 1) << 6, wn = (w >> 1) << 6;
  const int proj = (KIND == 1) ? (gy >> 3) : 0;
  const bool swp = (KIND == 0) || (proj < 2);

  const int srow = lane >> 3;
  const int gch  = (lane & 7) ^ (srow & 7);
  const u16* aptr[4]; const u16* bptr[4];
  char* adst[4]; char* bdst[4];
  #pragma unroll
  for (int u = 0; u < 4; ++u) {
    const int rl = w * 32 + u * 8 + srow;
    aptr[u] = Ag + (size_t)(row0 + rl) * 1024 + gch * 8;
    bptr[u] = Bg + (size_t)(col0 + rl) * 1024 + gch * 8;
    adst[u] = (char*)As + (w * 32 + u * 8) * 128;
    bdst[u] = (char*)Bs + (w * 32 + u * 8) * 128;
  }
  int aoff[2][4], boff[2][4];
  #pragma unroll
  for (int ks = 0; ks < 2; ++ks)
    #pragma unroll
    for (int q = 0; q < 4; ++q) {
      const int ra = wm + q * 16 + lt;
      aoff[ks][q] = ra * 128 + (((ks * 4 + lg) ^ (ra & 7)) << 4);
      const int rb = wn + q * 16 + lt;
      boff[ks][q] = rb * 128 + (((ks * 4 + lg) ^ (rb & 7)) << 4);
    }

  f32x4 acc[4][4];
  #pragma unroll
  for (int i = 0; i < 4; ++i)
    #pragma unroll
    for (int j = 0; j < 4; ++j) acc[i][j] = (f32x4){0.f,0.f,0.f,0.f};

  auto loop = [&](auto SW) {
    for (int kt = 0; kt < 16; ++kt) {
      #pragma unroll
      for (int u = 0; u < 4; ++u) {
        gl_lds16(aptr[u] + kt * 64, adst[u]);
        gl_lds16(bptr[u] + kt * 64, bdst[u]);
      }
      __syncthreads();
      #pragma unroll
      for (int ks = 0; ks < 2; ++ks) {
        short8 af[4], bf[4];
        #pragma unroll
        for (int q = 0; q < 4; ++q) {
          af[q] = *(const short8*)((const char*)As + aoff[ks][q]);
          bf[q] = *(const short8*)((const char*)Bs + boff[ks][q]);
        }
        #pragma unroll
        for (int mi = 0; mi < 4; ++mi)
          #pragma unroll
          for (int nj = 0; nj < 4; ++nj) {
            if constexpr (decltype(SW)::value)
              acc[mi][nj] = __builtin_amdgcn_mfma_f32_16x16x32_bf16(bf[nj], af[mi], acc[mi][nj], 0, 0, 0);
            else
              acc[mi][nj] = __builtin_amdgcn_mfma_f32_16x16x32_bf16(af[mi], bf[nj], acc[mi][nj], 0, 0, 0);
          }
      }
      __syncthreads();
    }
  };
  if (swp) loop(BC<true>{}); else loop(BC<false>{});

  if constexpr (KIND == 0) {
    #pragma unroll
    for (int mi = 0; mi < 4; ++mi) {
      const int m = row0 + wm + mi * 16 + lt;
      #pragma unroll
      for (int nj = 0; nj < 4; ++nj) {
        const int nb = col0 + wn + nj * 16 + (lg << 2);
        float4 bb = *(const float4*)(b0 + nb);
        nt_store4(acc[mi][nj][0] + bb.x, acc[mi][nj][1] + bb.y,
                  acc[mi][nj][2] + bb.z, acc[mi][nj][3] + bb.w,
                  Cout + (size_t)m * 1024 + nb);
      }
    }
  } else if (proj < 2) {
    const float* bias = proj ? b1 : b0;
    u16* Ob = proj ? O1 : O0;
    const int col0p = (gy & 7) << 7;
    #pragma unroll
    for (int mi = 0; mi < 4; ++mi) {
      const int m = row0 + wm + mi * 16 + lt;
      const int bb_ = m >> 11, lpos = m & (L_ - 1);
      #pragma unroll
      for (int nj = 0; nj < 4; ++nj) {
        const int nb = col0p + wn + nj * 16 + (lg << 2);
        const int d0 = nb & 63, h = nb >> 6;
        float4 ba = *(const float4*)(bias + nb);
        const float o0 = acc[mi][nj][0] + ba.x, o1 = acc[mi][nj][1] + ba.y;
        const float o2 = acc[mi][nj][2] + ba.z, o3 = acc[mi][nj][3] + ba.w;
        const float* ct = costab + lpos * 32 + (d0 >> 1);
        const float* st = sintab + lpos * 32 + (d0 >> 1);
        const float c0 = ct[0], c1 = ct[1], s0 = st[0], s1 = st[1];
        const float r0 = o0 * c0 - o1 * s0, r1 = o0 * s0 + o1 * c0;
        const float r2 = o2 * c1 - o3 * s1, r3 = o2 * s1 + o3 * c1;
        *(u16x4*)(Ob + ((size_t)(bb_ * 16 + h) * L_ + lpos) * 64 + d0) = f2b4(r0, r1, r2, r3);
      }
    }
  } else {
    const int col0p = (gy & 7) << 7;
    #pragma unroll
    for (int mi = 0; mi < 4; ++mi) {
      const int lb = row0 + wm + mi * 16 + (lg << 2);
      const int bb_ = lb >> 11;
      #pragma unroll
      for (int nj = 0; nj < 4; ++nj) {
        const int n = col0p + wn + nj * 16 + lt;
        const int h = n >> 6, dh = n & 63;
        const float bv1 = b2[n];
        *(u16x4*)(O2 + ((size_t)(bb_ * 16 + h) * 64 + dh) * L_ + (lb & (L_ - 1))) =
            f2b4(acc[mi][nj][0] + bv1, acc[mi][nj][1] + bv1,
                 acc[mi][nj][2] + bv1, acc[mi][nj][3] + bv1);
      }
    }
  }
}

// ---------------------------------------------------------------- MFMA attention
// Phase 1: stripe A compute (pooled, 8 waves) -> lsumA -> barrier.
// Phase 2: stripe B compute; each tile's K/V loads are followed by up to 6
//          stripe-A NT store chunks (stores are youngest VMEM ops -> in-order
//          vmcnt retirement means they never block load consumption; they
//          drain under B's MFMA/exp).
// Phase 3: lsumB -> barrier -> stripe B store. Phase 4: PV reduce + AO.
__global__ __launch_bounds__(512, 4) void attn_mfma(
    const u16* __restrict__ Qb, const u16* __restrict__ Kb, const u16* __restrict__ Vt,
    const float* __restrict__ pbg, float* __restrict__ Pout, u16* __restrict__ AOb)
{
  __shared__ u16 PL[33 * 16 * 64];        // 67584 B
  __shared__ float PVacc[2][16][64];      // 8192 B = 2048 floats; doubles as pbl pre-reduce
  __shared__ float lsbuf[8][2][16];       // 1024 B
  float* pbl = &PVacc[0][0][0];
  const int t = threadIdx.x, w = t >> 6, lane = t & 63;
  const int lt = lane & 15, lg = lane >> 4;
  *(float4*)(pbl + t * 4) = *(const float4*)(pbg + t * 4);
  const int wg = blockIdx.x + (blockIdx.y << 6);
  const int sid = (wg & 7) * 256 + (wg >> 3);
  const int bh = sid >> 6, pr = sid & 63;
  const int b = bh >> 4, h = bh & 15;
  const int sA = pr, sB = 127 - pr;
  const int kvA = (sA >> 2) + 1, kvB = (sB >> 2) + 1;
  const int swz = (lt & 7) << 4;
  const float C1 = 0.18033688011112042f;  // 0.125 * log2(e)
  char* PLb = (char*)PL;
  __syncthreads();                         // pbl visible

  f32x4 oaccA[4], oaccB[4];
  #pragma unroll
  for (int dt = 0; dt < 4; ++dt) {
    oaccA[dt] = (f32x4){0.f,0.f,0.f,0.f};
    oaccB[dt] = (f32x4){0.f,0.f,0.f,0.f};
  }
  float lsumA = 0.f, lsumB = 0.f;

  auto tile = [&](int s, int kvt, const short8& q0, const short8& q1,
                  f32x4* oacc, float& lsum, int pb0, int rstride, bool masked) {
    const int j0 = kvt << 6;
    const int i  = s * 16 + lt;
    const u16* kp = Kb + ((size_t)bh * L_ + j0 + lt) * 64 + lg * 8;
    short8 kf[8];
    #pragma unroll
    for (int jt = 0; jt < 4; ++jt) {
      kf[2*jt]   = *(const short8*)(kp + jt * 1024);
      kf[2*jt+1] = *(const short8*)(kp + jt * 1024 + 32);
    }
    f32x4 z[4];
    #pragma unroll
    for (int jt = 0; jt < 4; ++jt) {
      f32x4 zz = (f32x4){0.f,0.f,0.f,0.f};
      zz = __builtin_amdgcn_mfma_f32_16x16x32_bf16(kf[2*jt],   q0, zz, 0, 0, 0);
      zz = __builtin_amdgcn_mfma_f32_16x16x32_bf16(kf[2*jt+1], q1, zz, 0, 0, 0);
      z[jt] = zz;
    }
    const u16* vp = Vt + ((size_t)bh * 64 + lt) * L_ + j0 + lg * 8;
    short8 vf[8];
    #pragma unroll
    for (int dt = 0; dt < 4; ++dt) {
      vf[2*dt]   = *(const short8*)(vp + dt * 16 * L_);
      vf[2*dt+1] = *(const short8*)(vp + dt * 16 * L_ + 32);
    }
    #pragma unroll
    for (int jt = 0; jt < 4; ++jt) {
      const int jb = j0 + jt * 16 + (lg << 2);
      const int dd = i - jb;
      float pr4[4];
      if (masked) {
        #pragma unroll
        for (int r = 0; r < 4; ++r) {
          const int d  = dd - r;
          const int dc = d < 0 ? 0 : d;
          const float pe = exp2f(fmaf(z[jt][r], C1, pbl[dc]));
          pr4[r] = d < 0 ? 0.f : pe;
          lsum += pr4[r];
        }
      } else {
        #pragma unroll
        for (int r = 0; r < 4; ++r) {
          pr4[r] = exp2f(fmaf(z[jt][r], C1, pbl[dd - r]));
          lsum += pr4[r];
        }
      }
      *(u16x4*)(PLb + pb0 + lt * rstride + ((kvt * 128 + jt * 32 + lg * 8) ^ swz)) =
          f2b4(pr4[0], pr4[1], pr4[2], pr4[3]);
    }
    short8 pa0 = *(const short8*)(PLb + pb0 + lt * rstride + ((kvt * 128 + lg * 16) ^ swz));
    short8 pa1 = *(const short8*)(PLb + pb0 + lt * rstride + ((kvt * 128 + 64 + lg * 16) ^ swz));
    #pragma unroll
    for (int dt = 0; dt < 4; ++dt) {
      oacc[dt] = __builtin_amdgcn_mfma_f32_16x16x32_bf16(pa0, vf[2*dt],   oacc[dt], 0, 0, 0);
      oacc[dt] = __builtin_amdgcn_mfma_f32_16x16x32_bf16(pa1, vf[2*dt+1], oacc[dt], 0, 0, 0);
    }
  };

  // ---- phase 1: stripe A compute (pooled over 8 waves)
  {
    const u16* qpA = Qb + ((size_t)bh * L_ + sA * 16 + lt) * 64 + lg * 8;
    const short8 qA0 = *(const short8*)(qpA), qA1 = *(const short8*)(qpA + 32);
    for (int kvt = w; kvt < kvA; kvt += 8)
      tile(sA, kvt, qA0, qA1, oaccA, lsumA, 0, kvA << 7, kvt == kvA - 1);
  }
  lsumA += __shfl_xor(lsumA, 16); lsumA += __shfl_xor(lsumA, 32);
  if (lane < 16) lsbuf[w][0][lt] = lsumA;
  __syncthreads();   // lsumA complete; stripe A P in LDS final

  // ---- stripe A store prep: this wave owns stripe-A rows w*2, w*2+1
  float rvA[2]; const char* rbA[2]; float* prowA[2]; int limA[2], rswA[2];
  #pragma unroll
  for (int u = 0; u < 2; ++u) {
    const int rl = w * 2 + u;
    float den = 0.f;
    #pragma unroll
    for (int ww = 0; ww < 8; ++ww) den += lsbuf[ww][0][rl];
    rvA[u] = 1.f / den;
    rbA[u] = PLb + rl * (kvA << 7);
    rswA[u] = (rl & 7) << 4;
    const int i = sA * 16 + rl;
    limA[u] = i >> 2;
    prowA[u] = Pout + ((size_t)bh * L_ + i) * L_;
  }
  int chunk = 0;
  auto storeA = [&](int c) {
    const int u = c >> 3, cc = c & 7;
    const int c4 = lane + cc * 64;
    float ox = 0.f, oy = 0.f, oz = 0.f, ow = 0.f;
    if (c4 <= limA[u]) {
      u16x4 dv = *(const u16x4*)(rbA[u] + ((c4 << 3) ^ rswA[u]));
      const float rv = rvA[u];
      ox = bf2f(dv.x) * rv; oy = bf2f(dv.y) * rv;
      oz = bf2f(dv.z) * rv; ow = bf2f(dv.w) * rv;
      if (c4 == limA[u]) {
        const int i = sA * 16 + (w * 2 + u);
        const int j0c = c4 << 2;
        if (j0c + 1 > i) oy = 0.f;
        if (j0c + 2 > i) oz = 0.f;
        if (j0c + 3 > i) ow = 0.f;
      }
    }
    nt_store4(ox, oy, oz, ow, prowA[u] + (c4 << 2));
  };

  // ---- phase 2: stripe B compute with interleaved A stores
  {
    const u16* qpB = Qb + ((size_t)bh * L_ + sB * 16 + lt) * 64 + lg * 8;
    const short8 qB0 = *(const short8*)(qpB), qB1 = *(const short8*)(qpB + 32);
    const int pb0 = kvA << 11, rstride = kvB << 7;
    const int iB = sB * 16 + lt;
    for (int kvt = w; kvt < kvB; kvt += 8) {
      const bool masked = (kvt == kvB - 1);
      const int j0 = kvt << 6;
      const u16* kp = Kb + ((size_t)bh * L_ + j0 + lt) * 64 + lg * 8;
      short8 kf[8];
      #pragma unroll
      for (int jt = 0; jt < 4; ++jt) {
        kf[2*jt]   = *(const short8*)(kp + jt * 1024);
        kf[2*jt+1] = *(const short8*)(kp + jt * 1024 + 32);
      }
      f32x4 z[4];
      #pragma unroll
      for (int jt = 0; jt < 4; ++jt) {
        f32x4 zz = (f32x4){0.f,0.f,0.f,0.f};
        zz = __builtin_amdgcn_mfma_f32_16x16x32_bf16(kf[2*jt],   qB0, zz, 0, 0, 0);
        zz = __builtin_amdgcn_mfma_f32_16x16x32_bf16(kf[2*jt+1], qB1, zz, 0, 0, 0);
        z[jt] = zz;
      }
      const u16* vp = Vt + ((size_t)bh * 64 + lt) * L_ + j0 + lg * 8;
      short8 vf[8];
      #pragma unroll
      for (int dt = 0; dt < 4; ++dt) {
        vf[2*dt]   = *(const short8*)(vp + dt * 16 * L_);
        vf[2*dt+1] = *(const short8*)(vp + dt * 16 * L_ + 32);
      }
      // interleaved stripe-A stores (youngest VMEM ops: block nothing)
      {
        const int lim = (chunk + 6 < 16) ? chunk + 6 : 16;
        for (; chunk < lim; ++chunk) storeA(chunk);
      }
      #pragma unroll
      for (int jt = 0; jt < 4; ++jt) {
        const int jb = j0 + jt * 16 + (lg << 2);
        const int dd = iB - jb;
        float pr4[4];
        if (masked) {
          #pragma unroll
          for (int r = 0; r < 4; ++r) {
            const int d  = dd - r;
            const int dc = d < 0 ? 0 : d;
            const float pe = exp2f(fmaf(z[jt][r], C1, pbl[dc]));
            pr4[r] = d < 0 ? 0.f : pe;
            lsumB += pr4[r];
          }
        } else {
          #pragma unroll
          for (int r = 0; r < 4; ++r) {
            pr4[r] = exp2f(fmaf(z[jt][r], C1, pbl[dd - r]));
            lsumB += pr4[r];
          }
        }
        *(u16x4*)(PLb + pb0 + lt * rstride + ((kvt * 128 + jt * 32 + lg * 8) ^ swz)) =
            f2b4(pr4[0], pr4[1], pr4[2], pr4[3]);
      }
      short8 pa0 = *(const short8*)(PLb + pb0 + lt * rstride + ((kvt * 128 + lg * 16) ^ swz));
      short8 pa1 = *(const short8*)(PLb + pb0 + lt * rstride + ((kvt * 128 + 64 + lg * 16) ^ swz));
      #pragma unroll
      for (int dt = 0; dt < 4; ++dt) {
        oaccB[dt] = __builtin_amdgcn_mfma_f32_16x16x32_bf16(pa0, vf[2*dt],   oaccB[dt], 0, 0, 0);
        oaccB[dt] = __builtin_amdgcn_mfma_f32_16x16x32_bf16(pa1, vf[2*dt+1], oaccB[dt], 0, 0, 0);
      }
    }
    // flush remaining A stores
    for (; chunk < 16; ++chunk) storeA(chunk);
  }

  // ---- phase 3: lsumB reduce, then stripe B store
  lsumB += __shfl_xor(lsumB, 16); lsumB += __shfl_xor(lsumB, 32);
  if (lane < 16) lsbuf[w][1][lt] = lsumB;
  __syncthreads();
  {
    #pragma unroll
    for (int u = 0; u < 2; ++u) {
      const int rl = w * 2 + u;
      float den = 0.f;
      #pragma unroll
      for (int ww = 0; ww < 8; ++ww) den += lsbuf[ww][1][rl];
      const float rv = 1.f / den;
      const char* rb = PLb + (kvA << 11) + rl * (kvB << 7);
      const int rsw = (rl & 7) << 4;
      const int i = sB * 16 + rl;
      float* prow = Pout + ((size_t)bh * L_ + i) * L_;
      const int lim4 = i >> 2;
      #pragma unroll
      for (int cc = 0; cc < 8; ++cc) {
        const int c4 = lane + cc * 64;
        float ox = 0.f, oy = 0.f, oz = 0.f, ow = 0.f;
        if (c4 <= lim4) {
          u16x4 dv = *(const u16x4*)(rb + ((c4 << 3) ^ rsw));
          ox = bf2f(dv.x) * rv; oy = bf2f(dv.y) * rv;
          oz = bf2f(dv.z) * rv; ow = bf2f(dv.w) * rv;
          if (c4 == lim4) {
            const int j0c = c4 << 2;
            if (j0c + 1 > i) oy = 0.f;
            if (j0c + 2 > i) oz = 0.f;
            if (j0c + 3 > i) ow = 0.f;
          }
        }
        nt_store4(ox, oy, oz, ow, prow + (c4 << 2));
      }
    }
  }

  // ---- phase 4: deterministic PV reduce (overwrites pbl alias) + AO
  for (int rr = 0; rr < 8; ++rr) {
    if (w == rr) {
      #pragma unroll
      for (int dt = 0; dt < 4; ++dt)
        #pragma unroll
        for (int r = 0; r < 4; ++r) {
          if (rr == 0) {
            PVacc[0][(lg << 2) + r][dt * 16 + lt] = oaccA[dt][r];
            PVacc[1][(lg << 2) + r][dt * 16 + lt] = oaccB[dt][r];
          } else {
            PVacc[0][(lg << 2) + r][dt * 16 + lt] += oaccA[dt][r];
            PVacc[1][(lg << 2) + r][dt * 16 + lt] += oaccB[dt][r];
          }
        }
    }
    __syncthreads();
  }
  {
    const int st = t >> 8, rl = (t >> 4) & 15, c0 = (t & 15) << 2;
    float den = 0.f;
    #pragma unroll
    for (int ww = 0; ww < 8; ++ww) den += lsbuf[ww][st][rl];
    const float rv = 1.f / den;
    const int s_ = st ? sB : sA;
    const int i = s_ * 16 + rl;
    u16x4 o = f2b4(PVacc[st][rl][c0] * rv, PVacc[st][rl][c0 + 1] * rv,
                   PVacc[st][rl][c0 + 2] * rv, PVacc[st][rl][c0 + 3] * rv);
    *(u16x4*)(AOb + ((size_t)(b * L_ + i)) * 1024 + h * 64 + c0) = o;
  }
}

// ---------------------------------------------------------------- launch
extern "C" void kernel_launch(void* const* d_in, const int* in_sizes, int n_in,
                              void* d_out, int out_size, void* d_ws, size_t ws_size,
                              hipStream_t stream) {
  const float* x  = (const float*)d_in[0];
  const float* Wq = (const float*)d_in[1];
  const float* bq = (const float*)d_in[2];
  const float* Wk = (const float*)d_in[3];
  const float* bk = (const float*)d_in[4];
  const float* Wv = (const float*)d_in[5];
  const float* bv = (const float*)d_in[6];
  const float* Wo = (const float*)d_in[7];
  const float* bo = (const float*)d_in[8];

  float* out  = (float*)d_out;
  float* Pout = out + (size_t)BL_ * D_;

  float* ws = (float*)d_ws;
  u16* XB  = (u16*)(ws + WS_XB);
  u16* WT4 = (u16*)(ws + WS_WT4);
  u16* QB  = (u16*)(ws + WS_QB);
  u16* KB  = (u16*)(ws + WS_KB);
  u16* VT  = (u16*)(ws + WS_VT);
  u16* AOB = (u16*)(ws + WS_AOB);
  float* cosT = ws + WS_COS;
  float* sinT = ws + WS_SIN;
  float* pblG = ws + WS_PBL;

  fill_tables<<<256, 256, 0, stream>>>(cosT, sinT, pblG);
  xcast<<<2048, 256, 0, stream>>>(x, XB);
  wtrans4<<<dim3(16,16,4), 256, 0, stream>>>(Wq, Wk, Wv, Wo, WT4);

  gemm_k<1><<<dim3(32,24), 256, 0, stream>>>(XB, WT4, bq, bk, bv, cosT, sinT,
                                             QB, KB, VT, nullptr);

  attn_mfma<<<dim3(64,32), 512, 0, stream>>>(QB, KB, VT, pblG, Pout, AOB);

  gemm_k<0><<<dim3(32,8), 256, 0, stream>>>(AOB, WT4 + (size_t)3*1024*1024, bo,
                                            nullptr, nullptr, nullptr, nullptr,
                                            nullptr, nullptr, nullptr, out);
}

// Round 14
// 251.376 us; speedup vs baseline: 1.1645x; 1.1645x over previous
//
#include <hip/hip_runtime.h>
#include <math.h>

#define B_  2
#define L_  2048
#define D_  1024
#define H_  16
#define DH_ 64
#define BL_ (B_*L_)   // 4096

typedef unsigned short u16;
typedef __attribute__((ext_vector_type(8))) short short8;
typedef __attribute__((ext_vector_type(4))) float f32x4;
typedef __attribute__((ext_vector_type(4))) unsigned short u16x4;

template<bool V> struct BC { static constexpr bool value = V; };

// ---- workspace offsets (floats)
#define WS_XB   0            // x bf16 [4096][1024]
#define WS_WT4  2097152      // Wt bf16 [4][1024][1024]
#define WS_QB   4194304      // [32][2048][64] bf16
#define WS_KB   6291456
#define WS_VT   8388608      // [32][64][2048] bf16
#define WS_AOB  10485760     // AO bf16 [4096][1024]
#define WS_COS  12582912     // [2048][32] f32
#define WS_SIN  12648448
#define WS_PBL  12713984     // [2048] f32 (pre-scaled by log2e)
// end ~12.72M floats ~ 50.9 MB

__device__ __forceinline__ u16 f2b(float f) {
  union { float f; unsigned u; } v; v.f = f;
  unsigned r = (v.u + 0x7fffu + ((v.u >> 16) & 1u)) >> 16;
  return (u16)r;
}
__device__ __forceinline__ u16x4 f2b4(float a, float b, float c, float d) {
  u16x4 u; u.x = f2b(a); u.y = f2b(b); u.z = f2b(c); u.w = f2b(d); return u;
}
__device__ __forceinline__ float bf2f(u16 u) {
  union { unsigned u; float f; } v; v.u = ((unsigned)u) << 16; return v.f;
}
__device__ __forceinline__ void gl_lds16(const void* g, void* l) {
  __builtin_amdgcn_global_load_lds(
      (const __attribute__((address_space(1))) unsigned int*)g,
      (__attribute__((address_space(3))) unsigned int*)l, 16, 0, 0);
}
__device__ __forceinline__ void nt_store4(float x, float y, float z, float w, float* p) {
  f32x4 v = (f32x4){x, y, z, w};
  __builtin_nontemporal_store(v, (f32x4*)p);
}

// ---------------------------------------------------------------- fused prep:
// blocks 0..2047: xcast ; 2048..3071: wtrans (4 weights) ; 3072..3327: tables
__global__ __launch_bounds__(256) void prep(
    const float* __restrict__ x, u16* __restrict__ xb,
    const float* __restrict__ W0, const float* __restrict__ W1,
    const float* __restrict__ W2, const float* __restrict__ W3,
    u16* __restrict__ Wt,
    float* __restrict__ costab, float* __restrict__ sintab, float* __restrict__ pbl)
{
  __shared__ u16 tt[64][80];
  const int blk = blockIdx.x;
  const int t = threadIdx.x;
  if (blk < 2048) {
    const size_t i = ((size_t)blk * 256 + t) * 8;
    float4 a = *(const float4*)(x + i);
    float4 b = *(const float4*)(x + i + 4);
    u16 us[8] = { f2b(a.x),f2b(a.y),f2b(a.z),f2b(a.w), f2b(b.x),f2b(b.y),f2b(b.z),f2b(b.w) };
    *(short8*)(xb + i) = *(short8*)us;
  } else if (blk < 3072) {
    const int r2 = blk - 2048;
    const int z = r2 >> 8, rem = r2 & 255;
    const float* W = (z == 0) ? W0 : (z == 1) ? W1 : (z == 2) ? W2 : W3;
    u16* Wtz = Wt + (size_t)z * 1024 * 1024;
    const int k0 = (rem & 15) << 6, n0 = (rem >> 4) << 6;
    {
      const int r = t >> 4, c4 = (t & 15) << 2;
      for (int rr = r; rr < 64; rr += 16) {
        float4 v = *(const float4*)(W + (size_t)(k0 + rr) * D_ + n0 + c4);
        tt[c4+0][rr] = f2b(v.x); tt[c4+1][rr] = f2b(v.y);
        tt[c4+2][rr] = f2b(v.z); tt[c4+3][rr] = f2b(v.w);
      }
    }
    __syncthreads();
    const int n = t >> 2, kc = (t & 3) << 4;
    u16* dst = Wtz + (size_t)(n0 + n) * D_ + k0 + kc;
    #pragma unroll
    for (int u = 0; u < 16; ++u) dst[u] = tt[n][kc + u];
  } else {
    const int idx = (blk - 3072) * 256 + t;
    if (idx < L_ * 32) {
      int l = idx >> 5, tp = idx & 31;
      double inv = pow(10000.0, -2.0 * (double)tp / 64.0);
      double th  = (double)l * inv;
      costab[idx] = (float)cos(th);
      sintab[idx] = (float)sin(th);
    }
    if (idx < L_) {
      double d = (double)idx;
      double v = 0.5  * cos(6.283185307179586 * d / 24.0)
               + 0.25 * cos(6.283185307179586 * d / 168.0);
      pbl[idx] = (float)(v * 1.4426950408889634);
    }
  }
}

// ---------------------------------------------------------------- bf16 MFMA GEMM, 128x128 tile, BK=64
// KIND 1: bx-major XCD swizzle — each XCD owns gy {3x,3x+1,3x+2}; consecutive
// blocks share one A-panel (L2-hot) and keep the 3 W-panels resident.
template<int KIND>
__global__ __launch_bounds__(256) void gemm_k(
    const u16* __restrict__ Ag, const u16* __restrict__ Bg,
    const float* __restrict__ b0, const float* __restrict__ b1, const float* __restrict__ b2,
    const float* __restrict__ costab, const float* __restrict__ sintab,
    u16* __restrict__ O0, u16* __restrict__ O1, u16* __restrict__ O2,
    float* __restrict__ Cout)
{
  __shared__ u16 As[8192];
  __shared__ u16 Bs[8192];
  const int t = threadIdx.x, w = t >> 6, lane = t & 63;
  const int lt = lane & 15, lg = lane >> 4;
  const int wg = blockIdx.x + (blockIdx.y << 5);
  int sid;
  if constexpr (KIND == 1) {
    const int xcd = wg & 7, q = wg >> 3;    // q in [0,96)
    const int bx = q / 3, g3 = q - bx * 3;
    sid = (xcd * 3 + g3) * 32 + bx;
  } else {
    sid = (wg & 7) * 32 + (wg >> 3);        // 256 blocks, 1 gy per XCD
  }
  const int row0 = (sid & 31) << 7;
  const int gy   = sid >> 5;
  const int col0 = gy << 7;
  const int wm = (w & 1) << 6, wn = (w >> 1) << 6;
  const int proj = (KIND == 1) ? (gy >> 3) : 0;
  const bool swp = (KIND == 0) || (proj < 2);

  const int srow = lane >> 3;
  const int gch  = (lane & 7) ^ (srow & 7);
  const u16* aptr[4]; const u16* bptr[4];
  char* adst[4]; char* bdst[4];
  #pragma unroll
  for (int u = 0; u < 4; ++u) {
    const int rl = w * 32 + u * 8 + srow;
    aptr[u] = Ag + (size_t)(row0 + rl) * 1024 + gch * 8;
    bptr[u] = Bg + (size_t)(col0 + rl) * 1024 + gch * 8;
    adst[u] = (char*)As + (w * 32 + u * 8) * 128;
    bdst[u] = (char*)Bs + (w * 32 + u * 8) * 128;
  }
  int aoff[2][4], boff[2][4];
  #pragma unroll
  for (int ks = 0; ks < 2; ++ks)
    #pragma unroll
    for (int q = 0; q < 4; ++q) {
      const int ra = wm + q * 16 + lt;
      aoff[ks][q] = ra * 128 + (((ks * 4 + lg) ^ (ra & 7)) << 4);
      const int rb = wn + q * 16 + lt;
      boff[ks][q] = rb * 128 + (((ks * 4 + lg) ^ (rb & 7)) << 4);
    }

  f32x4 acc[4][4];
  #pragma unroll
  for (int i = 0; i < 4; ++i)
    #pragma unroll
    for (int j = 0; j < 4; ++j) acc[i][j] = (f32x4){0.f,0.f,0.f,0.f};

  auto loop = [&](auto SW) {
    for (int kt = 0; kt < 16; ++kt) {
      #pragma unroll
      for (int u = 0; u < 4; ++u) {
        gl_lds16(aptr[u] + kt * 64, adst[u]);
        gl_lds16(bptr[u] + kt * 64, bdst[u]);
      }
      __syncthreads();
      #pragma unroll
      for (int ks = 0; ks < 2; ++ks) {
        short8 af[4], bf[4];
        #pragma unroll
        for (int q = 0; q < 4; ++q) {
          af[q] = *(const short8*)((const char*)As + aoff[ks][q]);
          bf[q] = *(const short8*)((const char*)Bs + boff[ks][q]);
        }
        #pragma unroll
        for (int mi = 0; mi < 4; ++mi)
          #pragma unroll
          for (int nj = 0; nj < 4; ++nj) {
            if constexpr (decltype(SW)::value)
              acc[mi][nj] = __builtin_amdgcn_mfma_f32_16x16x32_bf16(bf[nj], af[mi], acc[mi][nj], 0, 0, 0);
            else
              acc[mi][nj] = __builtin_amdgcn_mfma_f32_16x16x32_bf16(af[mi], bf[nj], acc[mi][nj], 0, 0, 0);
          }
      }
      __syncthreads();
    }
  };
  if (swp) loop(BC<true>{}); else loop(BC<false>{});

  if constexpr (KIND == 0) {
    #pragma unroll
    for (int mi = 0; mi < 4; ++mi) {
      const int m = row0 + wm + mi * 16 + lt;
      #pragma unroll
      for (int nj = 0; nj < 4; ++nj) {
        const int nb = col0 + wn + nj * 16 + (lg << 2);
        float4 bb = *(const float4*)(b0 + nb);
        nt_store4(acc[mi][nj][0] + bb.x, acc[mi][nj][1] + bb.y,
                  acc[mi][nj][2] + bb.z, acc[mi][nj][3] + bb.w,
                  Cout + (size_t)m * 1024 + nb);
      }
    }
  } else if (proj < 2) {
    const float* bias = proj ? b1 : b0;
    u16* Ob = proj ? O1 : O0;
    const int col0p = (gy & 7) << 7;
    #pragma unroll
    for (int mi = 0; mi < 4; ++mi) {
      const int m = row0 + wm + mi * 16 + lt;
      const int bb_ = m >> 11, lpos = m & (L_ - 1);
      #pragma unroll
      for (int nj = 0; nj < 4; ++nj) {
        const int nb = col0p + wn + nj * 16 + (lg << 2);
        const int d0 = nb & 63, h = nb >> 6;
        float4 ba = *(const float4*)(bias + nb);
        const float o0 = acc[mi][nj][0] + ba.x, o1 = acc[mi][nj][1] + ba.y;
        const float o2 = acc[mi][nj][2] + ba.z, o3 = acc[mi][nj][3] + ba.w;
        const float* ct = costab + lpos * 32 + (d0 >> 1);
        const float* st = sintab + lpos * 32 + (d0 >> 1);
        const float c0 = ct[0], c1 = ct[1], s0 = st[0], s1 = st[1];
        const float r0 = o0 * c0 - o1 * s0, r1 = o0 * s0 + o1 * c0;
        const float r2 = o2 * c1 - o3 * s1, r3 = o2 * s1 + o3 * c1;
        *(u16x4*)(Ob + ((size_t)(bb_ * 16 + h) * L_ + lpos) * 64 + d0) = f2b4(r0, r1, r2, r3);
      }
    }
  } else {
    const int col0p = (gy & 7) << 7;
    #pragma unroll
    for (int mi = 0; mi < 4; ++mi) {
      const int lb = row0 + wm + mi * 16 + (lg << 2);
      const int bb_ = lb >> 11;
      #pragma unroll
      for (int nj = 0; nj < 4; ++nj) {
        const int n = col0p + wn + nj * 16 + lt;
        const int h = n >> 6, dh = n & 63;
        const float bv1 = b2[n];
        *(u16x4*)(O2 + ((size_t)(bb_ * 16 + h) * 64 + dh) * L_ + (lb & (L_ - 1))) =
            f2b4(acc[mi][nj][0] + bv1, acc[mi][nj][1] + bv1,
                 acc[mi][nj][2] + bv1, acc[mi][nj][3] + bv1);
      }
    }
  }
}

// ---------------------------------------------------------------- MFMA attention (R12 version)
// single-pass, LDS-resident P; pb table in LDS (aliased onto PVacc);
// wave-per-row NT P streaming; XCD-swizzled block mapping.
__global__ __launch_bounds__(512, 4) void attn_mfma(
    const u16* __restrict__ Qb, const u16* __restrict__ Kb, const u16* __restrict__ Vt,
    const float* __restrict__ pbg, float* __restrict__ Pout, u16* __restrict__ AOb)
{
  __shared__ u16 PL[33 * 16 * 64];        // 67584 B
  __shared__ float PVacc[2][16][64];      // 8192 B = 2048 floats; doubles as pbl pre-reduce
  __shared__ float lsbuf[8][2][16];       // 1024 B
  float* pbl = &PVacc[0][0][0];
  const int t = threadIdx.x, w = t >> 6, lane = t & 63;
  const int lt = lane & 15, lg = lane >> 4;
  *(float4*)(pbl + t * 4) = *(const float4*)(pbg + t * 4);
  const int wg = blockIdx.x + (blockIdx.y << 6);
  const int sid = (wg & 7) * 256 + (wg >> 3);
  const int bh = sid >> 6, pr = sid & 63;
  const int b = bh >> 4, h = bh & 15;
  const int sA = pr, sB = 127 - pr;
  const int kvA = (sA >> 2) + 1, kvB = (sB >> 2) + 1;
  const int swz = (lt & 7) << 4;
  const float C1 = 0.18033688011112042f;  // 0.125 * log2(e)
  char* PLb = (char*)PL;
  __syncthreads();                         // pbl visible to all waves

  f32x4 oaccA[4], oaccB[4];
  #pragma unroll
  for (int dt = 0; dt < 4; ++dt) {
    oaccA[dt] = (f32x4){0.f,0.f,0.f,0.f};
    oaccB[dt] = (f32x4){0.f,0.f,0.f,0.f};
  }
  float lsumA = 0.f, lsumB = 0.f;

  auto tile = [&](int s, int kvt, const short8& q0, const short8& q1,
                  f32x4* oacc, float& lsum, int pb0, int rstride, bool masked) {
    const int j0 = kvt << 6;
    const int i  = s * 16 + lt;
    const u16* kp = Kb + ((size_t)bh * L_ + j0 + lt) * 64 + lg * 8;
    short8 kf[8];
    #pragma unroll
    for (int jt = 0; jt < 4; ++jt) {
      kf[2*jt]   = *(const short8*)(kp + jt * 1024);
      kf[2*jt+1] = *(const short8*)(kp + jt * 1024 + 32);
    }
    f32x4 z[4];
    #pragma unroll
    for (int jt = 0; jt < 4; ++jt) {
      f32x4 zz = (f32x4){0.f,0.f,0.f,0.f};
      zz = __builtin_amdgcn_mfma_f32_16x16x32_bf16(kf[2*jt],   q0, zz, 0, 0, 0);
      zz = __builtin_amdgcn_mfma_f32_16x16x32_bf16(kf[2*jt+1], q1, zz, 0, 0, 0);
      z[jt] = zz;
    }
    const u16* vp = Vt + ((size_t)bh * 64 + lt) * L_ + j0 + lg * 8;
    short8 vf[8];
    #pragma unroll
    for (int dt = 0; dt < 4; ++dt) {
      vf[2*dt]   = *(const short8*)(vp + dt * 16 * L_);
      vf[2*dt+1] = *(const short8*)(vp + dt * 16 * L_ + 32);
    }
    #pragma unroll
    for (int jt = 0; jt < 4; ++jt) {
      const int jb = j0 + jt * 16 + (lg << 2);
      const int dd = i - jb;
      float pr4[4];
      if (masked) {
        #pragma unroll
        for (int r = 0; r < 4; ++r) {
          const int d  = dd - r;
          const int dc = d < 0 ? 0 : d;
          const float pe = exp2f(fmaf(z[jt][r], C1, pbl[dc]));
          pr4[r] = d < 0 ? 0.f : pe;
          lsum += pr4[r];
        }
      } else {
        #pragma unroll
        for (int r = 0; r < 4; ++r) {
          pr4[r] = exp2f(fmaf(z[jt][r], C1, pbl[dd - r]));
          lsum += pr4[r];
        }
      }
      *(u16x4*)(PLb + pb0 + lt * rstride + ((kvt * 128 + jt * 32 + lg * 8) ^ swz)) =
          f2b4(pr4[0], pr4[1], pr4[2], pr4[3]);
    }
    short8 pa0 = *(const short8*)(PLb + pb0 + lt * rstride + ((kvt * 128 + lg * 16) ^ swz));
    short8 pa1 = *(const short8*)(PLb + pb0 + lt * rstride + ((kvt * 128 + 64 + lg * 16) ^ swz));
    #pragma unroll
    for (int dt = 0; dt < 4; ++dt) {
      oacc[dt] = __builtin_amdgcn_mfma_f32_16x16x32_bf16(pa0, vf[2*dt],   oacc[dt], 0, 0, 0);
      oacc[dt] = __builtin_amdgcn_mfma_f32_16x16x32_bf16(pa1, vf[2*dt+1], oacc[dt], 0, 0, 0);
    }
  };

  // stripe A
  {
    const u16* qpA = Qb + ((size_t)bh * L_ + sA * 16 + lt) * 64 + lg * 8;
    const short8 qA0 = *(const short8*)(qpA), qA1 = *(const short8*)(qpA + 32);
    for (int kvt = w; kvt < kvA; kvt += 8)
      tile(sA, kvt, qA0, qA1, oaccA, lsumA, 0, kvA << 7, kvt == kvA - 1);
  }
  // stripe B (continue round-robin so every wave gets 4-5 total tiles)
  {
    const u16* qpB = Qb + ((size_t)bh * L_ + sB * 16 + lt) * 64 + lg * 8;
    const short8 qB0 = *(const short8*)(qpB), qB1 = *(const short8*)(qpB + 32);
    const int st0 = (8 + w - (kvA & 7)) & 7;
    for (int kvt = st0; kvt < kvB; kvt += 8)
      tile(sB, kvt, qB0, qB1, oaccB, lsumB, kvA << 11, kvB << 7, kvt == kvB - 1);
  }

  // per-wave lsum partials -> LDS
  lsumA += __shfl_xor(lsumA, 16); lsumA += __shfl_xor(lsumA, 32);
  lsumB += __shfl_xor(lsumB, 16); lsumB += __shfl_xor(lsumB, 32);
  if (lane < 16) { lsbuf[w][0][lt] = lsumA; lsbuf[w][1][lt] = lsumB; }
  __syncthreads();

  // ---- streaming P FIRST (non-temporal, wave-per-row: 1KB contiguous stores)
  #pragma unroll
  for (int rp = 0; rp < 4; ++rp) {
    const int rid = rp * 8 + w;             // 0..31
    const int st = rid >> 4, rl = rid & 15;
    const int s_ = st ? sB : sA;
    const int i  = s_ * 16 + rl;
    float den = 0.f;
    #pragma unroll
    for (int ww = 0; ww < 8; ++ww) den += lsbuf[ww][st][rl];
    const float rv = 1.f / den;
    const char* rb = PLb + (st ? (kvA << 11) : 0) + rl * ((st ? kvB : kvA) << 7);
    const int rsw = (rl & 7) << 4;
    float* prow = Pout + ((size_t)bh * L_ + i) * L_;
    const int lim4 = i >> 2;
    #pragma unroll
    for (int cc = 0; cc < 8; ++cc) {
      const int c4 = lane + cc * 64;
      float ox = 0.f, oy = 0.f, oz = 0.f, ow = 0.f;
      if (c4 <= lim4) {
        u16x4 dv = *(const u16x4*)(rb + ((c4 << 3) ^ rsw));
        ox = bf2f(dv.x) * rv; oy = bf2f(dv.y) * rv;
        oz = bf2f(dv.z) * rv; ow = bf2f(dv.w) * rv;
        if (c4 == lim4) {
          const int j0c = c4 << 2;
          if (j0c + 1 > i) oy = 0.f;
          if (j0c + 2 > i) oz = 0.f;
          if (j0c + 3 > i) ow = 0.f;
        }
      }
      nt_store4(ox, oy, oz, ow, prow + (c4 << 2));
    }
  }

  // ---- deterministic PV reduce (8 rounds), overlapped with store drain
  // (round 0 '=' overwrites the pbl alias — pbl no longer needed)
  for (int rr = 0; rr < 8; ++rr) {
    if (w == rr) {
      #pragma unroll
      for (int dt = 0; dt < 4; ++dt)
        #pragma unroll
        for (int r = 0; r < 4; ++r) {
          if (rr == 0) {
            PVacc[0][(lg << 2) + r][dt * 16 + lt] = oaccA[dt][r];
            PVacc[1][(lg << 2) + r][dt * 16 + lt] = oaccB[dt][r];
          } else {
            PVacc[0][(lg << 2) + r][dt * 16 + lt] += oaccA[dt][r];
            PVacc[1][(lg << 2) + r][dt * 16 + lt] += oaccB[dt][r];
          }
        }
    }
    __syncthreads();
  }

  // ---- AO write (normalized; cached — re-read by out-projection GEMM)
  {
    const int st = t >> 8, rl = (t >> 4) & 15, c0 = (t & 15) << 2;
    float den = 0.f;
    #pragma unroll
    for (int ww = 0; ww < 8; ++ww) den += lsbuf[ww][st][rl];
    const float rv = 1.f / den;
    const int s_ = st ? sB : sA;
    const int i = s_ * 16 + rl;
    u16x4 o = f2b4(PVacc[st][rl][c0] * rv, PVacc[st][rl][c0 + 1] * rv,
                   PVacc[st][rl][c0 + 2] * rv, PVacc[st][rl][c0 + 3] * rv);
    *(u16x4*)(AOb + ((size_t)(b * L_ + i)) * 1024 + h * 64 + c0) = o;
  }
}

// ---------------------------------------------------------------- launch
extern "C" void kernel_launch(void* const* d_in, const int* in_sizes, int n_in,
                              void* d_out, int out_size, void* d_ws, size_t ws_size,
                              hipStream_t stream) {
  const float* x  = (const float*)d_in[0];
  const float* Wq = (const float*)d_in[1];
  const float* bq = (const float*)d_in[2];
  const float* Wk = (const float*)d_in[3];
  const float* bk = (const float*)d_in[4];
  const float* Wv = (const float*)d_in[5];
  const float* bv = (const float*)d_in[6];
  const float* Wo = (const float*)d_in[7];
  const float* bo = (const float*)d_in[8];

  float* out  = (float*)d_out;
  float* Pout = out + (size_t)BL_ * D_;

  float* ws = (float*)d_ws;
  u16* XB  = (u16*)(ws + WS_XB);
  u16* WT4 = (u16*)(ws + WS_WT4);
  u16* QB  = (u16*)(ws + WS_QB);
  u16* KB  = (u16*)(ws + WS_KB);
  u16* VT  = (u16*)(ws + WS_VT);
  u16* AOB = (u16*)(ws + WS_AOB);
  float* cosT = ws + WS_COS;
  float* sinT = ws + WS_SIN;
  float* pblG = ws + WS_PBL;

  prep<<<3328, 256, 0, stream>>>(x, XB, Wq, Wk, Wv, Wo, WT4, cosT, sinT, pblG);

  gemm_k<1><<<dim3(32,24), 256, 0, stream>>>(XB, WT4, bq, bk, bv, cosT, sinT,
                                             QB, KB, VT, nullptr);

  attn_mfma<<<dim3(64,32), 512, 0, stream>>>(QB, KB, VT, pblG, Pout, AOB);

  gemm_k<0><<<dim3(32,8), 256, 0, stream>>>(AOB, WT4 + (size_t)3*1024*1024, bo,
                                            nullptr, nullptr, nullptr, nullptr,
                                            nullptr, nullptr, nullptr, out);
}